// Round 6
// baseline (200.767 us; speedup 1.0000x reference)
//
#include <hip/hip_runtime.h>
#include <hip/hip_fp16.h>

#define BB   4
#define FF   128
#define CC   8
#define LSEQ 196608        // 256*256*3
#define NCH  2048
#define CL   96            // LSEQ / NCH
#define TL   16            // positions per tile (= MFMA M)
#define NT   6             // CL / TL

typedef _Float16 half8 __attribute__((ext_vector_type(8)));
typedef float    f32x4 __attribute__((ext_vector_type(4)));

// ---------------- K1: per-chunk feature sums ----------------
__global__ __launch_bounds__(64) void k_chunksum(
    const int* __restrict__ ex, const float* __restrict__ W_in,
    const float* __restrict__ b_in, const float* __restrict__ pos,
    float* __restrict__ csum)
{
    __shared__ float xv[BB][CL];
    const int ch = blockIdx.x;
    const int t  = threadIdx.x;
    const int l0 = ch * CL;
    #pragma unroll
    for (int b = 0; b < BB; ++b)
        for (int i = t; i < CL; i += 64)
            xv[b][i] = (float)ex[(size_t)b * LSEQ + l0 + i] * 0.5f - 3.0f;
    __syncthreads();

    const float2 w  = *(const float2*)&W_in[2 * t];
    const float2 bb = *(const float2*)&b_in[2 * t];
    float2 s[BB];
    #pragma unroll
    for (int b = 0; b < BB; ++b) { s[b].x = 0.f; s[b].y = 0.f; }
    const float* pp = pos + (size_t)l0 * FF + 2 * t;
    #pragma unroll 4
    for (int l = 0; l < CL; ++l) {
        float2 p = *(const float2*)pp; pp += FF;
        float px = p.x + bb.x, py = p.y + bb.y;
        #pragma unroll
        for (int b = 0; b < BB; ++b) {
            float x = xv[b][l];
            s[b].x += fmaxf(fmaf(x, w.x, px), 0.f);
            s[b].y += fmaxf(fmaf(x, w.y, py), 0.f);
        }
    }
    #pragma unroll
    for (int b = 0; b < BB; ++b)
        *(float2*)&csum[((size_t)b * NCH + ch) * FF + 2 * t] = s[b];
}

// ---------------- K2 (merged): serial exclusive scan over 2048 chunks ----
// grid = BB blocks x 64 threads; lane owns feature pair (2t, 2t+1).
// Loads are address-independent -> pipelined; serial acc chain ~4cyc/step.
__global__ __launch_bounds__(64) void k_scan2(float* __restrict__ csum)
{
    const int b = blockIdx.x, t = threadIdx.x;
    float2 acc = {0.f, 0.f};
    float* p = csum + (size_t)b * NCH * FF + 2 * t;
    #pragma unroll 4
    for (int ch = 0; ch < NCH; ++ch) {
        float2 v = *(float2*)p;
        *(float2*)p = acc;
        acc.x += v.x; acc.y += v.y;
        p += FF;
    }
}

// ---------------- K3: scan + normalize + final dense (MFMA) ----------------
// 4 waves, wave = batch, ALL state wave-private -> ZERO barriers.
// Phase A: lane = feature-pair; scan 16 positions (direct float2 pos loads),
//          f16 store into XOR-swizzled [16][128] tile (byte ^= (row&7)<<4).
// Phase B: A-frag = ds_read_b128; Y = mfma(A, Wf_frag); Q = diag(mfma(A, A));
//          q broadcast via ds_bpermute.
// Out: transpose through 2KB LDS tbuf (wave-private, in-order DS pipe),
//      lanes 0-15 store one 32B row each via 2x dwordx4 (contiguous 512B).
__global__ __launch_bounds__(256, 4) void k_final(
    const int* __restrict__ ex, const float* __restrict__ W_in,
    const float* __restrict__ b_in, const float* __restrict__ pos,
    const float* __restrict__ Wf, const float* __restrict__ bfin,
    const float* __restrict__ csum, float* __restrict__ out)
{
    __shared__ __align__(16) __half stile[BB][TL][FF];   // 16 KB
    __shared__ __align__(16) float  tbuf[BB][TL][CC];    // 2 KB
    __shared__ float xv[BB][CL];                          // 1.5 KB

    const int ch   = blockIdx.x;
    const int l0   = ch * CL;
    const int t    = threadIdx.x;
    const int b    = t >> 6;       // wave = batch
    const int lane = t & 63;
    const int lo   = lane & 15;
    const int hi   = lane >> 4;

    // stage xv for this wave's batch (wave-private rows; same-wave read later)
    for (int i = lane; i < CL; i += 64)
        xv[b][i] = (float)ex[(size_t)b * LSEQ + l0 + i] * 0.5f - 3.0f;

    // Wf B-fragments (f16), cols >= 8 zeroed.  B layout: col=lane&15, k=(lane>>4)*8+j
    half8 wfrag[4];
    float bfc = (lo < CC) ? bfin[lo] : 0.f;
    #pragma unroll
    for (int kk = 0; kk < 4; ++kk) {
        #pragma unroll
        for (int j = 0; j < 8; ++j) {
            int k = kk * 32 + hi * 8 + j;
            float wv = (lo < CC) ? Wf[k * CC + lo] : 0.f;
            wfrag[kk][j] = (_Float16)wv;
        }
    }

    const float2 w  = *(const float2*)&W_in[2 * lane];
    const float2 bb = *(const float2*)&b_in[2 * lane];
    float2 s = *(const float2*)&csum[((size_t)b * NCH + ch) * FF + 2 * lane];

    char* sbase = (char*)&stile[b][0][0];
    // phase-B A-frag base byte offset (row = lo): kk advances via XOR of bit 6
    const int ra0 = lo * 256 + ((hi * 16) ^ ((lo & 7) << 4));
    const int wa  = 4 * lane;   // phase-A write offset before row-swizzle

    #pragma unroll 2
    for (int tile = 0; tile < NT; ++tile) {
        // ---- phase A: scan TL positions, lane = feature-pair, 1 batch ----
        const float* pp = pos + (size_t)(l0 + tile * TL) * FF + 2 * lane;
        #pragma unroll
        for (int l = 0; l < TL; ++l) {
            float2 p = *(const float2*)pp; pp += FF;
            float x = xv[b][tile * TL + l];
            s.x = fmaxf(fmaf(x, w.x, p.x + bb.x), 0.f) + s.x;
            s.y = fmaxf(fmaf(x, w.y, p.y + bb.y), 0.f) + s.y;
            __half2 h = __float22half2_rn(make_float2(s.x, s.y));
            *(__half2*)(sbase + l * 256 + (wa ^ ((l & 7) << 4))) = h;
        }

        // ---- phase B: MFMA matvec + self-dot ----
        f32x4 y  = {0.f, 0.f, 0.f, 0.f};
        f32x4 c2 = {0.f, 0.f, 0.f, 0.f};
        #pragma unroll
        for (int kk = 0; kk < 4; ++kk) {
            half8 a = *(half8*)(sbase + (ra0 ^ (kk << 6)));
            y  = __builtin_amdgcn_mfma_f32_16x16x32_f16(a, wfrag[kk], y, 0, 0, 0);
            c2 = __builtin_amdgcn_mfma_f32_16x16x32_f16(a, a,        c2, 0, 0, 0);
        }

        // q = diag(C2): row r's diag sits at lane r+16*(r>>2), reg r-4*(r>>2)
        int i0 = lo - 4 * hi;
        float qd = c2[0];
        qd = (i0 == 1) ? c2[1] : qd;
        qd = (i0 == 2) ? c2[2] : qd;
        qd = (i0 == 3) ? c2[3] : qd;
        float rr = rsqrtf(fmaxf(qd, 1e-12f));
        // rows 4*hi+i sourced from lane 20*hi+i
        int sl = 80 * hi;   // byte index = lane*4
        float r0 = __int_as_float(__builtin_amdgcn_ds_bpermute(sl,      __float_as_int(rr)));
        float r1 = __int_as_float(__builtin_amdgcn_ds_bpermute(sl + 4,  __float_as_int(rr)));
        float r2 = __int_as_float(__builtin_amdgcn_ds_bpermute(sl + 8,  __float_as_int(rr)));
        float r3 = __int_as_float(__builtin_amdgcn_ds_bpermute(sl + 12, __float_as_int(rr)));

        // ---- transpose through LDS (wave-private; DS pipe is in-order) ----
        if (lo < CC) {
            tbuf[b][4 * hi + 0][lo] = fmaf(y[0], r0, bfc);
            tbuf[b][4 * hi + 1][lo] = fmaf(y[1], r1, bfc);
            tbuf[b][4 * hi + 2][lo] = fmaf(y[2], r2, bfc);
            tbuf[b][4 * hi + 3][lo] = fmaf(y[3], r3, bfc);
        }
        // lanes 0-15 each store one 32B row; 16 lanes -> 512B contiguous
        if (lane < TL) {
            const f32x4* tp = (const f32x4*)&tbuf[b][lane][0];
            f32x4 v0 = tp[0], v1 = tp[1];
            float* op = out + (((size_t)b * LSEQ) + l0 + tile * TL + lane) * CC;
            *(f32x4*)op       = v0;
            *(f32x4*)(op + 4) = v1;
        }
    }
}

extern "C" void kernel_launch(void* const* d_in, const int* in_sizes, int n_in,
                              void* d_out, int out_size, void* d_ws, size_t ws_size,
                              hipStream_t stream) {
    const int*   ex   = (const int*)d_in[0];
    const float* W_in = (const float*)d_in[1];
    const float* b_in = (const float*)d_in[2];
    const float* pos  = (const float*)d_in[3];
    const float* Wf   = (const float*)d_in[4];
    const float* bf   = (const float*)d_in[5];
    float* out  = (float*)d_out;
    float* csum = (float*)d_ws;                       // [B][NCH][F] = 4 MB

    k_chunksum<<<NCH, 64, 0, stream>>>(ex, W_in, b_in, pos, csum);
    k_scan2   <<<BB, 64, 0, stream>>>(csum);
    k_final   <<<NCH, 256, 0, stream>>>(ex, W_in, b_in, pos, Wf, bf, csum, out);
}

// Round 7
// 68.835 us; speedup vs baseline: 2.9166x; 2.9166x over previous
//
#include <hip/hip_runtime.h>
#include <hip/hip_fp16.h>

#define BB   4
#define FF   128
#define CC   8
#define LSEQ 196608        // 256*256*3
#define NCH  2048
#define CL   96            // LSEQ / NCH
#define TL   16            // positions per tile (= MFMA M)
#define NT   6             // CL / TL
#define NSEG 32
#define SEGL 64            // NCH / NSEG
#define TS   12            // tbuf row stride (floats): 8 y + 1 q + 3 pad

typedef _Float16 half8 __attribute__((ext_vector_type(8)));
typedef float    f32x4 __attribute__((ext_vector_type(4)));

// ---------------- K1: per-chunk feature sums ----------------
__global__ __launch_bounds__(64) void k_chunksum(
    const int* __restrict__ ex, const float* __restrict__ W_in,
    const float* __restrict__ b_in, const float* __restrict__ pos,
    float* __restrict__ csum)
{
    __shared__ float xv[BB][CL];
    const int ch = blockIdx.x;
    const int t  = threadIdx.x;
    const int l0 = ch * CL;
    #pragma unroll
    for (int b = 0; b < BB; ++b)
        for (int i = t; i < CL; i += 64)
            xv[b][i] = (float)ex[(size_t)b * LSEQ + l0 + i] * 0.5f - 3.0f;
    __syncthreads();

    const float2 w  = *(const float2*)&W_in[2 * t];
    const float2 bb = *(const float2*)&b_in[2 * t];
    float2 s[BB];
    #pragma unroll
    for (int b = 0; b < BB; ++b) { s[b].x = 0.f; s[b].y = 0.f; }
    const float* pp = pos + (size_t)l0 * FF + 2 * t;
    #pragma unroll 4
    for (int l = 0; l < CL; ++l) {
        float2 p = *(const float2*)pp; pp += FF;
        float px = p.x + bb.x, py = p.y + bb.y;
        #pragma unroll
        for (int b = 0; b < BB; ++b) {
            float x = xv[b][l];
            s[b].x += fmaxf(fmaf(x, w.x, px), 0.f);
            s[b].y += fmaxf(fmaf(x, w.y, py), 0.f);
        }
    }
    #pragma unroll
    for (int b = 0; b < BB; ++b)
        *(float2*)&csum[((size_t)b * NCH + ch) * FF + 2 * t] = s[b];
}

// ---------------- K2a: segment totals ----------------
__global__ __launch_bounds__(128) void k_segsum(
    const float* __restrict__ csum, float* __restrict__ segT)
{
    const int seg = blockIdx.x, b = blockIdx.y, f = threadIdx.x;
    const float* p = csum + ((size_t)b * NCH + (size_t)seg * SEGL) * FF + f;
    float a = 0.f;
    #pragma unroll 8
    for (int i = 0; i < SEGL; ++i) a += p[(size_t)i * FF];
    segT[((size_t)b * NSEG + seg) * FF + f] = a;
}

// ---------------- K2b: exclusive scan of segment totals ----------------
__global__ __launch_bounds__(128) void k_segscan(float* __restrict__ segT)
{
    const int b = blockIdx.x, f = threadIdx.x;
    float acc = 0.f;
    for (int s = 0; s < NSEG; ++s) {
        size_t idx = ((size_t)b * NSEG + s) * FF + f;
        float v = segT[idx];
        segT[idx] = acc;
        acc += v;
    }
}

// ---------------- K2c: exclusive-ize chunk sums ----------------
__global__ __launch_bounds__(128) void k_chscan(
    float* __restrict__ csum, const float* __restrict__ segT)
{
    const int seg = blockIdx.x, b = blockIdx.y, f = threadIdx.x;
    float acc = segT[((size_t)b * NSEG + seg) * FF + f];
    float* p = csum + ((size_t)b * NCH + (size_t)seg * SEGL) * FF + f;
    #pragma unroll 8
    for (int i = 0; i < SEGL; ++i) {
        float v = p[(size_t)i * FF];
        p[(size_t)i * FF] = acc;
        acc += v;
    }
}

// ---------------- K3: scan + normalize + final dense (MFMA) ----------------
// 4 waves, wave = batch, wave-private, zero barriers. DS-pipe minimized:
//  - ex read via wave-uniform scalar loads (SMEM pipe, not DS)
//  - phase A: 16 ds_write_b32 into XOR-swizzled f16 stile
//  - phase B: 4 ds_read_b128 + 2 MFMA/kk; raw y + diag q through tbuf;
//    rsqrt+bias applied by the 16 store lanes (no ds_bpermute).
__global__ __launch_bounds__(256, 4) void k_final(
    const int* __restrict__ ex, const float* __restrict__ W_in,
    const float* __restrict__ b_in, const float* __restrict__ pos,
    const float* __restrict__ Wf, const float* __restrict__ bfin,
    const float* __restrict__ csum, float* __restrict__ out)
{
    __shared__ __align__(16) __half stile[BB][TL][FF];   // 16 KB
    __shared__ __align__(16) float  tbuf[BB][TL][TS];    // 3 KB

    const int ch   = blockIdx.x;
    const int l0   = ch * CL;
    const int t    = threadIdx.x;
    const int b    = __builtin_amdgcn_readfirstlane(t >> 6);   // wave = batch
    const int lane = t & 63;
    const int lo   = lane & 15;
    const int hi   = lane >> 4;

    // wave-uniform ex base -> scalar loads (SMEM pipe)
    const int* exu = ex + (size_t)b * LSEQ + l0;

    // Wf B-fragments (f16), cols >= 8 zeroed.  B layout: col=lane&15, k=(lane>>4)*8+j
    half8 wfrag[4];
    #pragma unroll
    for (int kk = 0; kk < 4; ++kk) {
        #pragma unroll
        for (int j = 0; j < 8; ++j) {
            int k = kk * 32 + hi * 8 + j;
            float wv = (lo < CC) ? Wf[k * CC + lo] : 0.f;
            wfrag[kk][j] = (_Float16)wv;
        }
    }
    // bias vectors (uniform scalar loads)
    const f32x4 bf0 = *(const f32x4*)&bfin[0];
    const f32x4 bf1 = *(const f32x4*)&bfin[4];

    const float2 w  = *(const float2*)&W_in[2 * lane];
    const float2 bb = *(const float2*)&b_in[2 * lane];
    float2 s = *(const float2*)&csum[((size_t)b * NCH + ch) * FF + 2 * lane];

    char* sbase = (char*)&stile[b][0][0];
    // phase-B A-frag base byte offset (row = lo): kk advances via XOR of bit 6
    const int ra0 = lo * 256 + ((hi * 16) ^ ((lo & 7) << 4));
    const int wa  = 4 * lane;   // phase-A write offset before row-swizzle

    const int jq = lo - 4 * hi;            // diag reg index if in [0,4)
    const bool isdiag = (jq >= 0) && (jq < 4);

    for (int tile = 0; tile < NT; ++tile) {
        // ---- phase A: scan TL positions, lane = feature-pair, 1 batch ----
        const float* pp = pos + (size_t)(l0 + tile * TL) * FF + 2 * lane;
        #pragma unroll
        for (int l = 0; l < TL; ++l) {
            float2 p = *(const float2*)pp; pp += FF;
            float x = (float)exu[tile * TL + l] * 0.5f - 3.0f;   // SGPR-sourced
            s.x = fmaxf(fmaf(x, w.x, p.x + bb.x), 0.f) + s.x;
            s.y = fmaxf(fmaf(x, w.y, p.y + bb.y), 0.f) + s.y;
            __half2 h = __float22half2_rn(make_float2(s.x, s.y));
            *(__half2*)(sbase + l * 256 + (wa ^ ((l & 7) << 4))) = h;
        }

        // ---- phase B: MFMA matvec + self-dot ----
        f32x4 y  = {0.f, 0.f, 0.f, 0.f};
        f32x4 c2 = {0.f, 0.f, 0.f, 0.f};
        #pragma unroll
        for (int kk = 0; kk < 4; ++kk) {
            half8 a = *(half8*)(sbase + (ra0 ^ (kk << 6)));
            y  = __builtin_amdgcn_mfma_f32_16x16x32_f16(a, wfrag[kk], y, 0, 0, 0);
            c2 = __builtin_amdgcn_mfma_f32_16x16x32_f16(a, a,        c2, 0, 0, 0);
        }

        // ---- transpose raw y + diag q through tbuf (wave-private, in-order DS) ----
        if (lo < CC) {
            tbuf[b][4 * hi + 0][lo] = y[0];
            tbuf[b][4 * hi + 1][lo] = y[1];
            tbuf[b][4 * hi + 2][lo] = y[2];
            tbuf[b][4 * hi + 3][lo] = y[3];
        }
        if (isdiag) {
            float qd = c2[0];
            qd = (jq == 1) ? c2[1] : qd;
            qd = (jq == 2) ? c2[2] : qd;
            qd = (jq == 3) ? c2[3] : qd;
            tbuf[b][lo][CC] = qd;          // q for row lo
        }
        // ---- store lanes: rsqrt + bias + 2x dwordx4 ----
        if (lane < TL) {
            const float* tr = &tbuf[b][lane][0];
            f32x4 v0 = *(const f32x4*)tr;
            f32x4 v1 = *(const f32x4*)(tr + 4);
            float rr = rsqrtf(fmaxf(tr[CC], 1e-12f));
            v0 = v0 * rr + bf0;
            v1 = v1 * rr + bf1;
            float* op = out + (((size_t)b * LSEQ) + l0 + tile * TL + lane) * CC;
            *(f32x4*)op       = v0;
            *(f32x4*)(op + 4) = v1;
        }
    }
}

extern "C" void kernel_launch(void* const* d_in, const int* in_sizes, int n_in,
                              void* d_out, int out_size, void* d_ws, size_t ws_size,
                              hipStream_t stream) {
    const int*   ex   = (const int*)d_in[0];
    const float* W_in = (const float*)d_in[1];
    const float* b_in = (const float*)d_in[2];
    const float* pos  = (const float*)d_in[3];
    const float* Wf   = (const float*)d_in[4];
    const float* bf   = (const float*)d_in[5];
    float* out  = (float*)d_out;
    float* csum = (float*)d_ws;                       // [B][NCH][F]  = 4 MB
    float* segT = csum + (size_t)BB * NCH * FF;       // [B][NSEG][F] = 64 KB

    k_chunksum<<<NCH, 64, 0, stream>>>(ex, W_in, b_in, pos, csum);
    k_segsum  <<<dim3(NSEG, BB), 128, 0, stream>>>(csum, segT);
    k_segscan <<<BB, 128, 0, stream>>>(segT);
    k_chscan  <<<dim3(NSEG, BB), 128, 0, stream>>>(csum, segT);
    k_final   <<<NCH, 256, 0, stream>>>(ex, W_in, b_in, pos, Wf, bf, csum, out);
}